// Round 5
// baseline (316.633 us; speedup 1.0000x reference)
//
#include <hip/hip_runtime.h>
#include <math.h>

#define NN   1024
#define HIDD 256
#define NH   8
#define NW   32   // 1024 bits / 32 per word

typedef __attribute__((ext_vector_type(8))) short short8;
typedef __attribute__((ext_vector_type(4))) float f32x4;

__device__ __forceinline__ float silu_f(float x) {
    return x / (1.0f + __expf(-x));
}
__device__ __forceinline__ unsigned short f2bf(float x) {
    unsigned b = __float_as_uint(x);
    return (unsigned short)((b + 0x7FFFu + ((b >> 16) & 1u)) >> 16);
}
__device__ __forceinline__ float bf2f(unsigned u) {
    return __uint_as_float(u << 16);
}

// ---------------- fused prep ----------------
// blocks [0,2048): convert src/tgt -> src_bf/tgt_bf/gateA
// blocks [2048,2304): transpose Wq/Wk/Wv/Wo (64 tiles each)
// blocks [2304,2816): transpose gaw1 (512x1024)
// block  2816: topo t01
// blocks [2817, 2817+nsc): scatter edges into p0/acol bit matrices

__global__ __launch_bounds__(256)
void prep_kernel(const float* __restrict__ src, const float* __restrict__ tgt,
                 const float* __restrict__ Wq, const float* __restrict__ Wk,
                 const float* __restrict__ Wv, const float* __restrict__ Wo,
                 const float* __restrict__ gaw1,
                 const float* __restrict__ tw1, const float* __restrict__ tb1,
                 const float* __restrict__ tw2, const float* __restrict__ tb2,
                 const int* __restrict__ ei, int E,
                 unsigned short* __restrict__ src_bf, unsigned short* __restrict__ tgt_bf,
                 unsigned short* __restrict__ gateA,
                 unsigned short* __restrict__ WqT, unsigned short* __restrict__ WkT,
                 unsigned short* __restrict__ WvT, unsigned short* __restrict__ WoT,
                 unsigned short* __restrict__ gaw1T,
                 float* __restrict__ t01,
                 unsigned* __restrict__ prow, unsigned* __restrict__ acol) {
    __shared__ float tile[32][33];
    int b = blockIdx.x, t = threadIdx.x;
    if (b < 2048) {
        int idx = b * 256 + t;
        int n = idx >> 9, j = idx & 511;
        if (j < 256) {
            unsigned short u = f2bf(src[n * 256 + j]);
            src_bf[n * 256 + j] = u;
            gateA[n * 512 + j]  = u;
        } else {
            int jj = j - 256;
            unsigned short u = f2bf(tgt[n * 256 + jj]);
            tgt_bf[n * 256 + jj] = u;
            gateA[n * 512 + j]   = u;
        }
    } else if (b < 2816) {
        const float* W; unsigned short* Wt; int Kd, Nd, n0, k0;
        if (b < 2304) {
            int b2 = b - 2048;
            int which = b2 >> 6, tl = b2 & 63;
            W  = (which == 0) ? Wq : (which == 1) ? Wk : (which == 2) ? Wv : Wo;
            Wt = (which == 0) ? WqT : (which == 1) ? WkT : (which == 2) ? WvT : WoT;
            Kd = 256; Nd = 256;
            n0 = (tl & 7) * 32; k0 = (tl >> 3) * 32;
        } else {
            int b2 = b - 2304;
            W = gaw1; Wt = gaw1T; Kd = 512; Nd = 1024;
            n0 = (b2 & 31) * 32; k0 = (b2 >> 5) * 32;
        }
        int tx = t & 31, ty = t >> 5;
        #pragma unroll
        for (int p = 0; p < 4; ++p)
            tile[ty + p * 8][tx] = W[(k0 + ty + p * 8) * (long)Nd + n0 + tx];
        __syncthreads();
        #pragma unroll
        for (int p = 0; p < 4; ++p)
            Wt[(n0 + ty + p * 8) * (long)Kd + k0 + tx] = f2bf(tile[tx][ty + p * 8]);
    } else if (b == 2816) {
        if (t < 16) {
            int h = t & 7;
            float x = (t >> 3) ? 1.0f : 0.0f;
            float acc = tb2[h];
            for (int c = 0; c < 32; ++c)
                acc += silu_f(x * tw1[c] + tb1[c]) * tw2[c * 8 + h];
            t01[t] = acc;
        }
    } else {
        int e = (b - 2817) * 256 + t;
        if (e < E) {
            int r = ei[e], c = ei[E + e];
            if ((unsigned)r < NN && (unsigned)c < NN) {
                atomicOr(&prow[r * NW + (c >> 5)], 1u << (c & 31));
                atomicOr(&acol[c * NW + (r >> 5)], 1u << (r & 31));
            }
        }
    }
}

// ---------------- path propagation: one row per block ----------------
// out[i,j] = in[i,j] & (OR_k in[i,k] & adj[k,j]); acol = adj^T rows (bits over k)

__global__ __launch_bounds__(256)
void path_iter_kernel(const unsigned* __restrict__ pin,
                      const unsigned* __restrict__ acol,
                      unsigned* __restrict__ pout) {
    __shared__ unsigned rowS[NW];
    __shared__ unsigned partial[8][NW];
    int i = blockIdx.x;
    int t = threadIdx.x;
    int wj = t & 31, sub = t >> 5;
    if (t < NW) rowS[t] = pin[i * NW + t];
    __syncthreads();
    uint4 pr[8];
    #pragma unroll
    for (int p = 0; p < 8; ++p) pr[p] = *(const uint4*)&rowS[p * 4];
    unsigned nib = 0u;
    #pragma unroll
    for (int bi = 0; bi < 4; ++bi) {
        int bpos = sub * 4 + bi;
        int j = (wj << 5) | bpos;
        const uint4* ac4 = (const uint4*)&acol[j * NW];
        unsigned x0 = 0, x1 = 0, x2 = 0, x3 = 0;
        #pragma unroll
        for (int p = 0; p < 8; ++p) {
            uint4 a = ac4[p];
            x0 |= pr[p].x & a.x;
            x1 |= pr[p].y & a.y;
            x2 |= pr[p].z & a.z;
            x3 |= pr[p].w & a.w;
        }
        nib |= (((x0 | x1) | (x2 | x3)) ? 1u : 0u) << bpos;
    }
    partial[sub][wj] = nib;
    __syncthreads();
    if (t < NW) {
        unsigned o = 0u;
        #pragma unroll
        for (int s = 0; s < 8; ++s) o |= partial[s][t];
        pout[i * NW + t] = rowS[t] & o;
    }
}

// ---------------- shared MFMA 64x64 tile ----------------
// Verified layouts: A[m=lane&15][k=quad*8+j]; B[k=quad*8+j][n=lane&15];
// C/D: col=lane&15, row=quad*4+reg.

__device__ __forceinline__ void mfma_tile64(const unsigned short* __restrict__ A,
                                            const unsigned short* __restrict__ Bt,
                                            int K, int i0, int j0, int t,
                                            f32x4 acc[2][2],
                                            unsigned short* As, unsigned short* Bs) {
    int l = t & 63, w = t >> 6;
    int wi = w >> 1, wj = w & 1;
    int quad = l >> 4, lj = l & 15;
    int sr = t >> 2, skp = (t & 3) * 8;
    f32x4 z = {0.f, 0.f, 0.f, 0.f};
    acc[0][0] = z; acc[0][1] = z; acc[1][0] = z; acc[1][1] = z;
    for (int k0 = 0; k0 < K; k0 += 32) {
        *(int4*)&As[sr * 32 + skp] = *(const int4*)&A[(i0 + sr) * (long)K + k0 + skp];
        *(int4*)&Bs[sr * 32 + skp] = *(const int4*)&Bt[(j0 + sr) * (long)K + k0 + skp];
        __syncthreads();
        short8 a0 = *(short8*)&As[(wi * 32 + lj) * 32 + quad * 8];
        short8 a1 = *(short8*)&As[(wi * 32 + 16 + lj) * 32 + quad * 8];
        short8 b0 = *(short8*)&Bs[(wj * 32 + lj) * 32 + quad * 8];
        short8 b1 = *(short8*)&Bs[(wj * 32 + 16 + lj) * 32 + quad * 8];
        acc[0][0] = __builtin_amdgcn_mfma_f32_16x16x32_bf16(a0, b0, acc[0][0], 0, 0, 0);
        acc[0][1] = __builtin_amdgcn_mfma_f32_16x16x32_bf16(a0, b1, acc[0][1], 0, 0, 0);
        acc[1][0] = __builtin_amdgcn_mfma_f32_16x16x32_bf16(a1, b0, acc[1][0], 0, 0, 0);
        acc[1][1] = __builtin_amdgcn_mfma_f32_16x16x32_bf16(a1, b1, acc[1][1], 0, 0, 0);
        __syncthreads();
    }
}

// ---------------- projections: QKV (192) + gate hidden w/ fused logits (256) --

__global__ __launch_bounds__(256)
void proj_kernel(const unsigned short* __restrict__ src_bf,
                 const unsigned short* __restrict__ tgt_bf,
                 const unsigned short* __restrict__ gateA,
                 const unsigned short* __restrict__ WqT,
                 const unsigned short* __restrict__ WkT,
                 const unsigned short* __restrict__ WvT,
                 const unsigned short* __restrict__ gaw1T,
                 const float* __restrict__ bq, const float* __restrict__ bk,
                 const float* __restrict__ bv, const float* __restrict__ gab1,
                 const float* __restrict__ gaw2,
                 unsigned short* __restrict__ q_bf, unsigned short* __restrict__ k_bf,
                 float* __restrict__ v_f, float* __restrict__ glog) {
    __shared__ unsigned short As[64 * 32];
    __shared__ unsigned short Bs[64 * 32];
    int b = blockIdx.x, t = threadIdx.x;
    int l = t & 63, w = t >> 6, wi = w >> 1, wjq = w & 1, quad = l >> 4, lj = l & 15;
    f32x4 acc[2][2];
    if (b < 192) {
        int z = b >> 6, rem = b & 63;
        int j0 = (rem & 3) * 64, i0 = (rem >> 2) * 64;
        const unsigned short* A  = (z == 0) ? src_bf : tgt_bf;
        const unsigned short* Bt = (z == 0) ? WqT : (z == 1) ? WkT : WvT;
        const float* bias        = (z == 0) ? bq : (z == 1) ? bk : bv;
        mfma_tile64(A, Bt, HIDD, i0, j0, t, acc, As, Bs);
        unsigned short* obf = (z == 0) ? q_bf : k_bf;
        #pragma unroll
        for (int rg = 0; rg < 2; ++rg)
            #pragma unroll
            for (int cg = 0; cg < 2; ++cg) {
                int col  = j0 + wjq * 32 + cg * 16 + lj;
                int row0 = i0 + wi * 32 + rg * 16 + quad * 4;
                float bb = bias[col];
                #pragma unroll
                for (int r = 0; r < 4; ++r) {
                    float v = acc[rg][cg][r] + bb;
                    if (z < 2) obf[(row0 + r) * HIDD + col] = f2bf(v);
                    else       v_f[(row0 + r) * HIDD + col] = v;
                }
            }
    } else {
        int b2 = b - 192;
        int j0 = (b2 & 15) * 64, i0 = (b2 >> 4) * 64;
        mfma_tile64(gateA, gaw1T, 512, i0, j0, t, acc, As, Bs);
        // silu + project onto gaw2 cols, reduce over the 16 lj lanes, atomicAdd rows
        float p[8][2];
        #pragma unroll
        for (int rg = 0; rg < 2; ++rg)
            #pragma unroll
            for (int r = 0; r < 4; ++r) { p[rg * 4 + r][0] = 0.f; p[rg * 4 + r][1] = 0.f; }
        #pragma unroll
        for (int cg = 0; cg < 2; ++cg) {
            int col = j0 + wjq * 32 + cg * 16 + lj;
            float w20 = gaw2[col * 2], w21 = gaw2[col * 2 + 1];
            float bb = gab1[col];
            #pragma unroll
            for (int rg = 0; rg < 2; ++rg)
                #pragma unroll
                for (int r = 0; r < 4; ++r) {
                    float hv = silu_f(acc[rg][cg][r] + bb);
                    p[rg * 4 + r][0] += hv * w20;
                    p[rg * 4 + r][1] += hv * w21;
                }
        }
        #pragma unroll
        for (int off = 1; off < 16; off <<= 1)
            #pragma unroll
            for (int s = 0; s < 8; ++s) {
                p[s][0] += __shfl_xor(p[s][0], off, 64);
                p[s][1] += __shfl_xor(p[s][1], off, 64);
            }
        if (lj == 0) {
            #pragma unroll
            for (int rg = 0; rg < 2; ++rg)
                #pragma unroll
                for (int r = 0; r < 4; ++r) {
                    int row = i0 + wi * 32 + rg * 16 + quad * 4 + r;
                    atomicAdd(&glog[row * 2],     p[rg * 4 + r][0]);
                    atomicAdd(&glog[row * 2 + 1], p[rg * 4 + r][1]);
                }
        }
    }
}

// ---------------- score via MFMA: 64x64 pair blocks, all 8 heads ----------------
// gate softmax computed inline from glog; geo table packed [h/2][pair] dwords.

__global__ __launch_bounds__(256)
void score_mfma_kernel(const unsigned short* __restrict__ qbf,
                       const unsigned short* __restrict__ kbf,
                       const float* __restrict__ pos, const float* __restrict__ glog,
                       const float* __restrict__ gab2,
                       const unsigned* __restrict__ pbits, const float* __restrict__ t01,
                       const float* __restrict__ gw1, const float* __restrict__ gb1,
                       const float* __restrict__ gw2, const float* __restrict__ gb2,
                       float* __restrict__ S) {
    __shared__ unsigned geo2[4 * 4096];        // 64 KB  [h/2][pair]
    __shared__ float posA[192], posB[192];
    __shared__ unsigned prowL[128];            // [i][word]
    __shared__ float g01[128];
    __shared__ float w1s[32], b1s[32], w2s[256], b2s[8], t01s[16];
    int t  = threadIdx.x;
    int n0 = blockIdx.y * 64, m0 = blockIdx.x * 64;
    w2s[t] = gw2[t];
    if (t < 192) { posA[t] = pos[n0 * 3 + t]; posB[t] = pos[m0 * 3 + t]; }
    if (t < 128) prowL[t] = pbits[(n0 + (t >> 1)) * NW + (m0 >> 5) + (t & 1)];
    if (t < 64) {
        float L0 = glog[(n0 + t) * 2]     + gab2[0];
        float L1 = glog[(n0 + t) * 2 + 1] + gab2[1];
        float mx = fmaxf(L0, L1);
        float e0 = __expf(L0 - mx), e1 = __expf(L1 - mx);
        float inv = 1.0f / (e0 + e1);
        g01[2 * t]     = e0 * inv;
        g01[2 * t + 1] = e1 * inv;
    }
    if (t < 32) { w1s[t] = gw1[t]; b1s[t] = gb1[t]; }
    if (t < 16) t01s[t] = t01[t];
    if (t < 8)  b2s[t] = gb2[t];
    __syncthreads();

    // phase 1: geo MLP, 16 pairs per thread
    for (int pp = 0; pp < 16; ++pp) {
        int p = pp * 256 + t;
        int i = p >> 6, j = p & 63;
        float dx = posA[i * 3]     - posB[j * 3];
        float dy = posA[i * 3 + 1] - posB[j * 3 + 1];
        float dz = posA[i * 3 + 2] - posB[j * 3 + 2];
        float dist = sqrtf(fmaxf(dx * dx + dy * dy + dz * dz, 1e-12f));
        float go[8];
        #pragma unroll
        for (int h = 0; h < 8; ++h) go[h] = b2s[h];
        #pragma unroll 4
        for (int c = 0; c < 32; ++c) {
            float hh = silu_f(dist * w1s[c] + b1s[c]);
            #pragma unroll
            for (int h = 0; h < 8; ++h) go[h] += hh * w2s[c * 8 + h];
        }
        #pragma unroll
        for (int h2 = 0; h2 < 4; ++h2)
            geo2[h2 * 4096 + p] = (unsigned)f2bf(go[2 * h2]) |
                                  ((unsigned)f2bf(go[2 * h2 + 1]) << 16);
    }
    __syncthreads();

    // phase 2: wave w owns local rows [w*16, w*16+16), all cols, all heads
    int l = t & 63, w = t >> 6, quad = l >> 4, lj = l & 15;
    const float scale = 0.17677669529663687f;  // 1/sqrt(32)
    for (int h = 0; h < 8; ++h) {
        short8 a = *(const short8*)&qbf[(n0 + w * 16 + lj) * HIDD + h * 32 + quad * 8];
        f32x4 z = {0.f, 0.f, 0.f, 0.f};
        f32x4 acc[4];
        #pragma unroll
        for (int cg = 0; cg < 4; ++cg) {
            short8 bfr = *(const short8*)&kbf[(m0 + cg * 16 + lj) * HIDD + h * 32 + quad * 8];
            acc[cg] = __builtin_amdgcn_mfma_f32_16x16x32_bf16(a, bfr, z, 0, 0, 0);
        }
        #pragma unroll
        for (int cg = 0; cg < 4; ++cg) {
            int j = cg * 16 + lj;
            #pragma unroll
            for (int r = 0; r < 4; ++r) {
                int i = w * 16 + quad * 4 + r;
                unsigned gv = geo2[(h >> 1) * 4096 + i * 64 + j];
                float geo_v = bf2f((h & 1) ? (gv >> 16) : (gv & 0xffffu));
                unsigned bit = (prowL[i * 2 + (j >> 5)] >> (j & 31)) & 1u;
                float val = acc[cg][r] * scale + g01[i * 2] * geo_v +
                            g01[i * 2 + 1] * t01s[bit * 8 + h];
                S[((long)h << 20) + (n0 + i) * NN + m0 + j] = val;
            }
        }
    }
}

// ---------------- softmax + PV, 8 rows per block; bf16 output ----------------

#define RG 8

__global__ __launch_bounds__(256)
void softpv_kernel(const float* __restrict__ S, const float* __restrict__ v,
                   unsigned short* __restrict__ out_bf) {
    __shared__ float sr[RG][NN];        // 32 KB
    __shared__ float part[8][RG][32];   // 8 KB
    __shared__ float invs[RG];
    int h  = blockIdx.x;
    int n0 = blockIdx.y * RG;
    int t  = threadIdx.x;
    const float4* S4 = (const float4*)(S + ((long)h << 20) + (long)n0 * NN);
    #pragma unroll
    for (int r = 0; r < RG; ++r)
        ((float4*)sr[r])[t] = S4[r * 256 + t];
    __syncthreads();
    {
        int wv = t >> 6, l = t & 63;
        #pragma unroll
        for (int rr = 0; rr < 2; ++rr) {
            int r = wv + rr * 4;
            float mx = -1e30f;
            #pragma unroll 4
            for (int m = l; m < NN; m += 64) mx = fmaxf(mx, sr[r][m]);
            #pragma unroll
            for (int off = 32; off > 0; off >>= 1) mx = fmaxf(mx, __shfl_xor(mx, off, 64));
            float sum = 0.0f;
            #pragma unroll 4
            for (int m = l; m < NN; m += 64) {
                float e = __expf(sr[r][m] - mx);
                sr[r][m] = e;
                sum += e;
            }
            #pragma unroll
            for (int off = 32; off > 0; off >>= 1) sum += __shfl_xor(sum, off, 64);
            if (l == 0) invs[r] = 1.0f / sum;
        }
    }
    __syncthreads();
    {
        int dd = t & 31, ch = t >> 5;
        float acc[RG] = {};
        const float* vp = v + (ch * 128) * HIDD + h * 32 + dd;
        #pragma unroll 4
        for (int i = 0; i < 128; ++i) {
            float vv = vp[i * HIDD];
            int m = ch * 128 + i;
            #pragma unroll
            for (int r = 0; r < RG; ++r) acc[r] += sr[r][m] * vv;
        }
        #pragma unroll
        for (int r = 0; r < RG; ++r) part[ch][r][dd] = acc[r];
    }
    __syncthreads();
    {
        int r = t >> 5, d2 = t & 31;
        float s = 0.0f;
        #pragma unroll
        for (int c = 0; c < 8; ++c) s += part[c][r][d2];
        out_bf[(n0 + r) * HIDD + h * 32 + d2] = f2bf(s * invs[r]);
    }
}

// ---------------- fused Wo projection + residual + LayerNorm ----------------

__global__ __launch_bounds__(256)
void wo_ln_kernel(const unsigned short* __restrict__ aout_bf,
                  const unsigned short* __restrict__ WoT,
                  const float* __restrict__ bo, const float* __restrict__ xres,
                  const float* __restrict__ lng, const float* __restrict__ lnb,
                  float* __restrict__ out) {
    __shared__ unsigned short Asm[16 * 264];
    __shared__ float Osm[16][260];
    __shared__ float Lg[256], Lb[256];
    int t = threadIdx.x;
    int r0 = blockIdx.x * 16;
    Lg[t] = lng[t]; Lb[t] = lnb[t];
    #pragma unroll
    for (int c = 0; c < 2; ++c) {
        int chunk = t * 2 + c;
        int row = chunk >> 5, off = (chunk & 31) * 8;
        *(int4*)&Asm[row * 264 + off] = *(const int4*)&aout_bf[(r0 + row) * HIDD + off];
    }
    __syncthreads();
    int l = t & 63, w = t >> 6, quad = l >> 4, lj = l & 15;
    f32x4 z = {0.f, 0.f, 0.f, 0.f};
    f32x4 acc[4] = {z, z, z, z};
    for (int ks = 0; ks < 8; ++ks) {
        short8 a = *(short8*)&Asm[lj * 264 + ks * 32 + quad * 8];
        #pragma unroll
        for (int nt = 0; nt < 4; ++nt) {
            int col = w * 64 + nt * 16 + lj;
            short8 bfr = *(const short8*)&WoT[col * HIDD + ks * 32 + quad * 8];
            acc[nt] = __builtin_amdgcn_mfma_f32_16x16x32_bf16(a, bfr, acc[nt], 0, 0, 0);
        }
    }
    #pragma unroll
    for (int nt = 0; nt < 4; ++nt) {
        int col = w * 64 + nt * 16 + lj;
        float bb = bo[col];
        #pragma unroll
        for (int r = 0; r < 4; ++r)
            Osm[quad * 4 + r][col] = acc[nt][r] + bb;
    }
    __syncthreads();
    #pragma unroll
    for (int rr = 0; rr < 4; ++rr) {
        int row = w * 4 + rr;
        float4 o  = *(float4*)&Osm[row][l * 4];
        float4 s4 = *(const float4*)&xres[(r0 + row) * HIDD + l * 4];
        float x0 = o.x + s4.x, x1 = o.y + s4.y, x2 = o.z + s4.z, x3 = o.w + s4.w;
        float sum = x0 + x1 + x2 + x3;
        float ss  = x0 * x0 + x1 * x1 + x2 * x2 + x3 * x3;
        #pragma unroll
        for (int off = 32; off > 0; off >>= 1) {
            sum += __shfl_xor(sum, off, 64);
            ss  += __shfl_xor(ss,  off, 64);
        }
        float mean = sum * (1.0f / HIDD);
        float var  = ss * (1.0f / HIDD) - mean * mean;
        float rstd = rsqrtf(var + 1e-5f);
        float4 ov;
        ov.x = (x0 - mean) * rstd * Lg[l * 4]     + Lb[l * 4];
        ov.y = (x1 - mean) * rstd * Lg[l * 4 + 1] + Lb[l * 4 + 1];
        ov.z = (x2 - mean) * rstd * Lg[l * 4 + 2] + Lb[l * 4 + 2];
        ov.w = (x3 - mean) * rstd * Lg[l * 4 + 3] + Lb[l * 4 + 3];
        *(float4*)&out[(r0 + row) * HIDD + l * 4] = ov;
    }
}

// ---------------- host ----------------

extern "C" void kernel_launch(void* const* d_in, const int* in_sizes, int n_in,
                              void* d_out, int out_size, void* d_ws, size_t ws_size,
                              hipStream_t stream) {
    const float* src  = (const float*)d_in[0];
    const float* tgt  = (const float*)d_in[1];
    const float* pos  = (const float*)d_in[2];
    const int*   ei   = (const int*)d_in[3];
    const float* Wq   = (const float*)d_in[4];  const float* bq  = (const float*)d_in[5];
    const float* Wk   = (const float*)d_in[6];  const float* bk  = (const float*)d_in[7];
    const float* Wv   = (const float*)d_in[8];  const float* bv  = (const float*)d_in[9];
    const float* gw1  = (const float*)d_in[10]; const float* gb1 = (const float*)d_in[11];
    const float* gw2  = (const float*)d_in[12]; const float* gb2 = (const float*)d_in[13];
    const float* tw1  = (const float*)d_in[14]; const float* tb1 = (const float*)d_in[15];
    const float* tw2  = (const float*)d_in[16]; const float* tb2 = (const float*)d_in[17];
    const float* gaw1 = (const float*)d_in[18]; const float* gab1= (const float*)d_in[19];
    const float* gaw2 = (const float*)d_in[20]; const float* gab2= (const float*)d_in[21];
    const float* Wo   = (const float*)d_in[22]; const float* bo  = (const float*)d_in[23];
    const float* lng  = (const float*)d_in[24]; const float* lnb = (const float*)d_in[25];
    int E = in_sizes[3] / 2;

    char* w = (char*)d_ws;
    unsigned* acol = (unsigned*)w; w += NN * NW * 4;        // zeroed
    unsigned* p0   = (unsigned*)w; w += NN * NW * 4;        // zeroed (contiguous)
    float* glog    = (float*)w;    w += NN * 2 * 4;         // zeroed (contiguous)
    unsigned* p1   = (unsigned*)w; w += NN * NW * 4;
    unsigned short* src_bf = (unsigned short*)w; w += NN * HIDD * 2;
    unsigned short* tgt_bf = (unsigned short*)w; w += NN * HIDD * 2;
    unsigned short* gateA  = (unsigned short*)w; w += NN * 512 * 2;
    unsigned short* WqT    = (unsigned short*)w; w += HIDD * HIDD * 2;
    unsigned short* WkT    = (unsigned short*)w; w += HIDD * HIDD * 2;
    unsigned short* WvT    = (unsigned short*)w; w += HIDD * HIDD * 2;
    unsigned short* WoT    = (unsigned short*)w; w += HIDD * HIDD * 2;
    unsigned short* gaw1T  = (unsigned short*)w; w += 1024 * 512 * 2;
    unsigned short* q_bf   = (unsigned short*)w; w += NN * HIDD * 2;
    unsigned short* k_bf   = (unsigned short*)w; w += NN * HIDD * 2;
    float* v_f  = (float*)w; w += NN * HIDD * 4;
    float* t01  = (float*)w; w += 256;
    unsigned short* aout_bf = (unsigned short*)w; w += NN * HIDD * 2;
    float* S    = (float*)w; w += (long)NH * NN * NN * 4;   // 32 MB

    int nsc = (E + 255) / 256;

    // zero acol + p0 + glog (contiguous)
    hipMemsetAsync(acol, 0, 2 * NN * NW * 4 + NN * 2 * 4, stream);

    // prep: converts + transposes + topo + edge scatter
    prep_kernel<<<2817 + nsc, 256, 0, stream>>>(src, tgt, Wq, Wk, Wv, Wo, gaw1,
                                                tw1, tb1, tw2, tb2, ei, E,
                                                src_bf, tgt_bf, gateA,
                                                WqT, WkT, WvT, WoT, gaw1T, t01,
                                                p0, acol);

    path_iter_kernel<<<NN, 256, 0, stream>>>(p0, acol, p1);
    path_iter_kernel<<<NN, 256, 0, stream>>>(p1, acol, p0);
    path_iter_kernel<<<NN, 256, 0, stream>>>(p0, acol, p1);   // final path in p1

    // QKV + gate hidden (logits fused via atomics into glog)
    proj_kernel<<<448, 256, 0, stream>>>(src_bf, tgt_bf, gateA, WqT, WkT, WvT, gaw1T,
                                         bq, bk, bv, gab1, gaw2,
                                         q_bf, k_bf, v_f, glog);

    // scores (gate softmax inline) -> softmax+PV
    score_mfma_kernel<<<dim3(16, 16), 256, 0, stream>>>(q_bf, k_bf, pos, glog, gab2,
                                                        p1, t01, gw1, gb1, gw2, gb2, S);
    softpv_kernel<<<dim3(NH, NN / RG), 256, 0, stream>>>(S, v_f, aout_bf);

    // Wo projection + residual + LN fused
    wo_ln_kernel<<<NN / 16, 256, 0, stream>>>(aout_bf, WoT, bo, src, lng, lnb,
                                              (float*)d_out);
}

// Round 6
// 289.563 us; speedup vs baseline: 1.0935x; 1.0935x over previous
//
#include <hip/hip_runtime.h>
#include <math.h>

#define NN   1024
#define HIDD 256
#define NH   8
#define NW   32   // 1024 bits / 32 per word

typedef __attribute__((ext_vector_type(8))) short short8;
typedef __attribute__((ext_vector_type(4))) float f32x4;

__device__ __forceinline__ float silu_f(float x) {
    return x / (1.0f + __expf(-x));
}
__device__ __forceinline__ unsigned short f2bf(float x) {
    unsigned b = __float_as_uint(x);
    return (unsigned short)((b + 0x7FFFu + ((b >> 16) & 1u)) >> 16);
}
__device__ __forceinline__ float bf2f(unsigned u) {
    return __uint_as_float(u << 16);
}

// ---------------- fused prep ----------------
// blocks [0,2048): convert src/tgt -> src_bf/tgt_bf/gateA
// blocks [2048,2304): transpose Wq/Wk/Wv/Wo
// blocks [2304,2816): transpose gaw1
// block  2816: topo t01
// blocks [2817,...): scatter edges into p0/acol bit matrices

__global__ __launch_bounds__(256)
void prep_kernel(const float* __restrict__ src, const float* __restrict__ tgt,
                 const float* __restrict__ Wq, const float* __restrict__ Wk,
                 const float* __restrict__ Wv, const float* __restrict__ Wo,
                 const float* __restrict__ gaw1,
                 const float* __restrict__ tw1, const float* __restrict__ tb1,
                 const float* __restrict__ tw2, const float* __restrict__ tb2,
                 const int* __restrict__ ei, int E,
                 unsigned short* __restrict__ src_bf, unsigned short* __restrict__ tgt_bf,
                 unsigned short* __restrict__ gateA,
                 unsigned short* __restrict__ WqT, unsigned short* __restrict__ WkT,
                 unsigned short* __restrict__ WvT, unsigned short* __restrict__ WoT,
                 unsigned short* __restrict__ gaw1T,
                 float* __restrict__ t01,
                 unsigned* __restrict__ prow, unsigned* __restrict__ acol) {
    __shared__ float tile[32][33];
    int b = blockIdx.x, t = threadIdx.x;
    if (b < 2048) {
        int idx = b * 256 + t;
        int n = idx >> 9, j = idx & 511;
        if (j < 256) {
            unsigned short u = f2bf(src[n * 256 + j]);
            src_bf[n * 256 + j] = u;
            gateA[n * 512 + j]  = u;
        } else {
            int jj = j - 256;
            unsigned short u = f2bf(tgt[n * 256 + jj]);
            tgt_bf[n * 256 + jj] = u;
            gateA[n * 512 + j]   = u;
        }
    } else if (b < 2816) {
        const float* W; unsigned short* Wt; int Kd, Nd, n0, k0;
        if (b < 2304) {
            int b2 = b - 2048;
            int which = b2 >> 6, tl = b2 & 63;
            W  = (which == 0) ? Wq : (which == 1) ? Wk : (which == 2) ? Wv : Wo;
            Wt = (which == 0) ? WqT : (which == 1) ? WkT : (which == 2) ? WvT : WoT;
            Kd = 256; Nd = 256;
            n0 = (tl & 7) * 32; k0 = (tl >> 3) * 32;
        } else {
            int b2 = b - 2304;
            W = gaw1; Wt = gaw1T; Kd = 512; Nd = 1024;
            n0 = (b2 & 31) * 32; k0 = (b2 >> 5) * 32;
        }
        int tx = t & 31, ty = t >> 5;
        #pragma unroll
        for (int p = 0; p < 4; ++p)
            tile[ty + p * 8][tx] = W[(k0 + ty + p * 8) * (long)Nd + n0 + tx];
        __syncthreads();
        #pragma unroll
        for (int p = 0; p < 4; ++p)
            Wt[(n0 + ty + p * 8) * (long)Kd + k0 + tx] = f2bf(tile[tx][ty + p * 8]);
    } else if (b == 2816) {
        if (t < 16) {
            int h = t & 7;
            float x = (t >> 3) ? 1.0f : 0.0f;
            float acc = tb2[h];
            for (int c = 0; c < 32; ++c)
                acc += silu_f(x * tw1[c] + tb1[c]) * tw2[c * 8 + h];
            t01[t] = acc;
        }
    } else {
        int e = (b - 2817) * 256 + t;
        if (e < E) {
            int r = ei[e], c = ei[E + e];
            if ((unsigned)r < NN && (unsigned)c < NN) {
                atomicOr(&prow[r * NW + (c >> 5)], 1u << (c & 31));
                atomicOr(&acol[c * NW + (r >> 5)], 1u << (r & 31));
            }
        }
    }
}

// ---------------- path propagation (R4 form: 8 rows / block) ----------------

__global__ __launch_bounds__(256)
void path_iter_kernel(const unsigned* __restrict__ pin,
                      const unsigned* __restrict__ acol,
                      unsigned* __restrict__ pout) {
    __shared__ unsigned pr8[8][NW];
    int t  = threadIdx.x;
    int ty = t >> 5;
    int wj = t & 31;
    int i  = blockIdx.x * 8 + ty;
    pr8[ty][wj] = pin[i * NW + wj];
    __syncthreads();
    uint4 pr[8];
    #pragma unroll
    for (int p = 0; p < 8; ++p) pr[p] = *(const uint4*)&pr8[ty][p * 4];
    unsigned inw  = pr8[ty][wj];
    unsigned outw = 0u;
    for (int b = 0; b < 32; ++b) {
        int j = (wj << 5) | b;
        const uint4* ac4 = (const uint4*)&acol[j * NW];
        unsigned x0 = 0, x1 = 0, x2 = 0, x3 = 0;
        #pragma unroll
        for (int p = 0; p < 8; ++p) {
            uint4 a = ac4[p];
            x0 |= pr[p].x & a.x;
            x1 |= pr[p].y & a.y;
            x2 |= pr[p].z & a.z;
            x3 |= pr[p].w & a.w;
        }
        outw |= (((x0 | x1) | (x2 | x3)) ? 1u : 0u) << b;
    }
    pout[i * NW + wj] = inw & outw;
}

// ---------------- shared MFMA 64x64 tile ----------------

__device__ __forceinline__ void mfma_tile64(const unsigned short* __restrict__ A,
                                            const unsigned short* __restrict__ Bt,
                                            int K, int i0, int j0, int t,
                                            f32x4 acc[2][2],
                                            unsigned short* As, unsigned short* Bs) {
    int l = t & 63, w = t >> 6;
    int wi = w >> 1, wj = w & 1;
    int quad = l >> 4, lj = l & 15;
    int sr = t >> 2, skp = (t & 3) * 8;
    f32x4 z = {0.f, 0.f, 0.f, 0.f};
    acc[0][0] = z; acc[0][1] = z; acc[1][0] = z; acc[1][1] = z;
    for (int k0 = 0; k0 < K; k0 += 32) {
        *(int4*)&As[sr * 32 + skp] = *(const int4*)&A[(i0 + sr) * (long)K + k0 + skp];
        *(int4*)&Bs[sr * 32 + skp] = *(const int4*)&Bt[(j0 + sr) * (long)K + k0 + skp];
        __syncthreads();
        short8 a0 = *(short8*)&As[(wi * 32 + lj) * 32 + quad * 8];
        short8 a1 = *(short8*)&As[(wi * 32 + 16 + lj) * 32 + quad * 8];
        short8 b0 = *(short8*)&Bs[(wj * 32 + lj) * 32 + quad * 8];
        short8 b1 = *(short8*)&Bs[(wj * 32 + 16 + lj) * 32 + quad * 8];
        acc[0][0] = __builtin_amdgcn_mfma_f32_16x16x32_bf16(a0, b0, acc[0][0], 0, 0, 0);
        acc[0][1] = __builtin_amdgcn_mfma_f32_16x16x32_bf16(a0, b1, acc[0][1], 0, 0, 0);
        acc[1][0] = __builtin_amdgcn_mfma_f32_16x16x32_bf16(a1, b0, acc[1][0], 0, 0, 0);
        acc[1][1] = __builtin_amdgcn_mfma_f32_16x16x32_bf16(a1, b1, acc[1][1], 0, 0, 0);
        __syncthreads();
    }
}

// ---------------- projections: QKV (192) + gate hidden w/ fused logits (256) --
// z==2 (v) stores TRANSPOSED bf16: vT[col][m]

__global__ __launch_bounds__(256)
void proj_kernel(const unsigned short* __restrict__ src_bf,
                 const unsigned short* __restrict__ tgt_bf,
                 const unsigned short* __restrict__ gateA,
                 const unsigned short* __restrict__ WqT,
                 const unsigned short* __restrict__ WkT,
                 const unsigned short* __restrict__ WvT,
                 const unsigned short* __restrict__ gaw1T,
                 const float* __restrict__ bq, const float* __restrict__ bk,
                 const float* __restrict__ bv, const float* __restrict__ gab1,
                 const float* __restrict__ gaw2,
                 unsigned short* __restrict__ q_bf, unsigned short* __restrict__ k_bf,
                 unsigned short* __restrict__ vT, float* __restrict__ glog) {
    __shared__ unsigned short As[64 * 32];
    __shared__ unsigned short Bs[64 * 32];
    int b = blockIdx.x, t = threadIdx.x;
    int l = t & 63, w = t >> 6, wi = w >> 1, wjq = w & 1, quad = l >> 4, lj = l & 15;
    f32x4 acc[2][2];
    if (b < 192) {
        int z = b >> 6, rem = b & 63;
        int j0 = (rem & 3) * 64, i0 = (rem >> 2) * 64;
        const unsigned short* A  = (z == 0) ? src_bf : tgt_bf;
        const unsigned short* Bt = (z == 0) ? WqT : (z == 1) ? WkT : WvT;
        const float* bias        = (z == 0) ? bq : (z == 1) ? bk : bv;
        mfma_tile64(A, Bt, HIDD, i0, j0, t, acc, As, Bs);
        #pragma unroll
        for (int rg = 0; rg < 2; ++rg)
            #pragma unroll
            for (int cg = 0; cg < 2; ++cg) {
                int col  = j0 + wjq * 32 + cg * 16 + lj;
                int row0 = i0 + wi * 32 + rg * 16 + quad * 4;
                float bb = bias[col];
                if (z < 2) {
                    unsigned short* obf = (z == 0) ? q_bf : k_bf;
                    #pragma unroll
                    for (int r = 0; r < 4; ++r)
                        obf[(row0 + r) * HIDD + col] = f2bf(acc[rg][cg][r] + bb);
                } else {
                    unsigned short vv[4];
                    #pragma unroll
                    for (int r = 0; r < 4; ++r) vv[r] = f2bf(acc[rg][cg][r] + bb);
                    // vT[col][row0..row0+3] contiguous 8B store
                    *(int2*)&vT[col * NN + row0] = *(int2*)vv;
                }
            }
    } else {
        int b2 = b - 192;
        int j0 = (b2 & 15) * 64, i0 = (b2 >> 4) * 64;
        mfma_tile64(gateA, gaw1T, 512, i0, j0, t, acc, As, Bs);
        float p[8][2];
        #pragma unroll
        for (int s = 0; s < 8; ++s) { p[s][0] = 0.f; p[s][1] = 0.f; }
        #pragma unroll
        for (int cg = 0; cg < 2; ++cg) {
            int col = j0 + wjq * 32 + cg * 16 + lj;
            float w20 = gaw2[col * 2], w21 = gaw2[col * 2 + 1];
            float bb = gab1[col];
            #pragma unroll
            for (int rg = 0; rg < 2; ++rg)
                #pragma unroll
                for (int r = 0; r < 4; ++r) {
                    float hv = silu_f(acc[rg][cg][r] + bb);
                    p[rg * 4 + r][0] += hv * w20;
                    p[rg * 4 + r][1] += hv * w21;
                }
        }
        #pragma unroll
        for (int off = 1; off < 16; off <<= 1)
            #pragma unroll
            for (int s = 0; s < 8; ++s) {
                p[s][0] += __shfl_xor(p[s][0], off, 64);
                p[s][1] += __shfl_xor(p[s][1], off, 64);
            }
        if (lj == 0) {
            #pragma unroll
            for (int rg = 0; rg < 2; ++rg)
                #pragma unroll
                for (int r = 0; r < 4; ++r) {
                    int row = i0 + wi * 32 + rg * 16 + quad * 4 + r;
                    atomicAdd(&glog[row * 2],     p[rg * 4 + r][0]);
                    atomicAdd(&glog[row * 2 + 1], p[rg * 4 + r][1]);
                }
        }
    }
}

// ---------------- flash attention: QK+bias+softmax(partial)+PV fused ----------
// grid (4 m-chunks, 64 row-tiles). Block: 16 rows x 256 m x 8 heads.
// Writes unnormalized partial O [chunk][n][256] + (m,l) stats [chunk][n][h].

#define PS 264   // Pb row stride (shorts), 16B-aligned rows

__global__ __launch_bounds__(256)
void flash_kernel(const unsigned short* __restrict__ qbf,
                  const unsigned short* __restrict__ kbf,
                  const unsigned short* __restrict__ vT,
                  const float* __restrict__ pos, const float* __restrict__ glog,
                  const float* __restrict__ gab2,
                  const unsigned* __restrict__ pbits, const float* __restrict__ t01,
                  const float* __restrict__ gw1, const float* __restrict__ gb1,
                  const float* __restrict__ gw2, const float* __restrict__ gb2,
                  float* __restrict__ Opart, float* __restrict__ ml) {
    __shared__ unsigned geo2[4 * 4096];        // 64 KB [h/2][i*256+j]
    __shared__ unsigned short Pb[16 * PS];     // 8.25 KB, A-layout P
    __shared__ float posA[48], posB[768];
    __shared__ unsigned prowL[128];            // [row][word] 16x8
    __shared__ float g01[32];
    __shared__ float redM[4 * 16], redL[4 * 16];
    __shared__ float w1s[32], b1s[32], w2s[256], b2s[8], t01s[16];
    int t  = threadIdx.x;
    int bx = blockIdx.x;               // m-chunk
    int n0 = blockIdx.y * 16;
    int mbase = bx * 256;
    w2s[t] = gw2[t];
    if (t < 48)  posA[t] = pos[n0 * 3 + t];
    { posB[t] = pos[mbase * 3 + t]; posB[256 + t] = pos[mbase * 3 + 256 + t];
      posB[512 + t] = pos[mbase * 3 + 512 + t]; }
    if (t < 128) prowL[t] = pbits[(n0 + (t >> 3)) * NW + bx * 8 + (t & 7)];
    if (t < 16) {
        float L0 = glog[(n0 + t) * 2]     + gab2[0];
        float L1 = glog[(n0 + t) * 2 + 1] + gab2[1];
        float mx = fmaxf(L0, L1);
        float e0 = __expf(L0 - mx), e1 = __expf(L1 - mx);
        float inv = 1.0f / (e0 + e1);
        g01[2 * t]     = e0 * inv;
        g01[2 * t + 1] = e1 * inv;
    }
    if (t < 32) { w1s[t] = gw1[t]; b1s[t] = gb1[t]; }
    if (t < 16) t01s[t] = t01[t];
    if (t < 8)  b2s[t] = gb2[t];
    __syncthreads();

    // phase 1: geo MLP, pairs p = i*256 + j, 16 per thread
    for (int pp = 0; pp < 16; ++pp) {
        int p = pp * 256 + t;
        int i = p >> 8, j = p & 255;
        float dx = posA[i * 3]     - posB[j * 3];
        float dy = posA[i * 3 + 1] - posB[j * 3 + 1];
        float dz = posA[i * 3 + 2] - posB[j * 3 + 2];
        float dist = sqrtf(fmaxf(dx * dx + dy * dy + dz * dz, 1e-12f));
        float go[8];
        #pragma unroll
        for (int h = 0; h < 8; ++h) go[h] = b2s[h];
        #pragma unroll 4
        for (int c = 0; c < 32; ++c) {
            float hh = silu_f(dist * w1s[c] + b1s[c]);
            #pragma unroll
            for (int h = 0; h < 8; ++h) go[h] += hh * w2s[c * 8 + h];
        }
        #pragma unroll
        for (int h2 = 0; h2 < 4; ++h2)
            geo2[h2 * 4096 + p] = (unsigned)f2bf(go[2 * h2]) |
                                  ((unsigned)f2bf(go[2 * h2 + 1]) << 16);
    }
    __syncthreads();

    int l = t & 63, w = t >> 6, quad = l >> 4, lj = l & 15;
    const float scale = 0.17677669529663687f;  // 1/sqrt(32)

    for (int h = 0; h < 8; ++h) {
        // QK: wave w covers m-cols [w*64, w*64+64), cg tiles of 16
        short8 a = *(const short8*)&qbf[(n0 + lj) * HIDD + h * 32 + quad * 8];
        f32x4 z = {0.f, 0.f, 0.f, 0.f};
        f32x4 acc[4];
        #pragma unroll
        for (int cg = 0; cg < 4; ++cg) {
            short8 bfr = *(const short8*)&kbf[(mbase + w * 64 + cg * 16 + lj) * HIDD +
                                              h * 32 + quad * 8];
            acc[cg] = __builtin_amdgcn_mfma_f32_16x16x32_bf16(a, bfr, z, 0, 0, 0);
        }
        // bias add (in C-layout regs): row i=quad*4+r, col j=w*64+cg*16+lj
        #pragma unroll
        for (int cg = 0; cg < 4; ++cg) {
            int j = w * 64 + cg * 16 + lj;
            #pragma unroll
            for (int r = 0; r < 4; ++r) {
                int i = quad * 4 + r;
                unsigned gv = geo2[(h >> 1) * 4096 + i * 256 + j];
                float geo_v = bf2f((h & 1) ? (gv >> 16) : (gv & 0xffffu));
                unsigned bit = (prowL[i * 8 + (j >> 5)] >> (j & 31)) & 1u;
                acc[cg][r] = acc[cg][r] * scale + g01[2 * i] * geo_v +
                             g01[2 * i + 1] * t01s[bit * 8 + h];
            }
        }
        // per-row max: lane-local over cg, shfl over the 16 lj lanes
        float mr[4];
        #pragma unroll
        for (int r = 0; r < 4; ++r)
            mr[r] = fmaxf(fmaxf(acc[0][r], acc[1][r]), fmaxf(acc[2][r], acc[3][r]));
        #pragma unroll
        for (int off = 1; off < 16; off <<= 1)
            #pragma unroll
            for (int r = 0; r < 4; ++r) mr[r] = fmaxf(mr[r], __shfl_xor(mr[r], off, 64));
        if (lj == 0) {
            #pragma unroll
            for (int r = 0; r < 4; ++r) redM[w * 16 + quad * 4 + r] = mr[r];
        }
        __syncthreads();
        float M[4];
        #pragma unroll
        for (int r = 0; r < 4; ++r) {
            int i = quad * 4 + r;
            M[r] = fmaxf(fmaxf(redM[i], redM[16 + i]), fmaxf(redM[32 + i], redM[48 + i]));
        }
        float sr_[4] = {0.f, 0.f, 0.f, 0.f};
        #pragma unroll
        for (int cg = 0; cg < 4; ++cg) {
            int j = w * 64 + cg * 16 + lj;
            #pragma unroll
            for (int r = 0; r < 4; ++r) {
                float e = __expf(acc[cg][r] - M[r]);
                Pb[(quad * 4 + r) * PS + j] = f2bf(e);
                sr_[r] += e;
            }
        }
        #pragma unroll
        for (int off = 1; off < 16; off <<= 1)
            #pragma unroll
            for (int r = 0; r < 4; ++r) sr_[r] += __shfl_xor(sr_[r], off, 64);
        if (lj == 0) {
            #pragma unroll
            for (int r = 0; r < 4; ++r) redL[w * 16 + quad * 4 + r] = sr_[r];
        }
        __syncthreads();
        // stats (redM/redL complete)
        if (t < 16) {
            float Mf = fmaxf(fmaxf(redM[t], redM[16 + t]), fmaxf(redM[32 + t], redM[48 + t]));
            float Lf = redL[t] + redL[16 + t] + redL[32 + t] + redL[48 + t];
            int base = ((bx * NN + n0 + t) * 8 + h) * 2;
            ml[base] = Mf; ml[base + 1] = Lf;
        }
        // PV: waves 0,1 -> d-tile w; A=P (rows via lj), B=vT rows (d via lj)
        if (w < 2) {
            f32x4 o = {0.f, 0.f, 0.f, 0.f};
            #pragma unroll
            for (int ks = 0; ks < 8; ++ks) {
                short8 aP = *(short8*)&Pb[lj * PS + ks * 32 + quad * 8];
                short8 bV = *(const short8*)&vT[(h * 32 + w * 16 + lj) * NN +
                                                mbase + ks * 32 + quad * 8];
                o = __builtin_amdgcn_mfma_f32_16x16x32_bf16(aP, bV, o, 0, 0, 0);
            }
            #pragma unroll
            for (int r = 0; r < 4; ++r)
                Opart[((long)(bx * NN + n0 + quad * 4 + r)) * HIDD + h * 32 + w * 16 + lj]
                    = o[r];
        }
        __syncthreads();
    }
}

// ---------------- combine + Wo projection + residual + LayerNorm ----------------

__global__ __launch_bounds__(256)
void wo_ln_kernel(const float* __restrict__ Opart, const float* __restrict__ ml,
                  const unsigned short* __restrict__ WoT,
                  const float* __restrict__ bo, const float* __restrict__ xres,
                  const float* __restrict__ lng, const float* __restrict__ lnb,
                  float* __restrict__ out) {
    __shared__ unsigned short Asm[16 * PS];
    __shared__ float Osm[16][260];
    __shared__ float Lg[256], Lb[256];
    __shared__ float wc[16][8][4];
    __shared__ float invl[16][8];
    int t = threadIdx.x;
    int r0 = blockIdx.x * 16;
    Lg[t] = lng[t]; Lb[t] = lnb[t];
    // combine stats
    if (t < 128) {
        int r = t >> 3, h = t & 7;
        float mm[4], ll[4];
        float M = -1e30f;
        #pragma unroll
        for (int ch = 0; ch < 4; ++ch) {
            int base = ((ch * NN + r0 + r) * 8 + h) * 2;
            mm[ch] = ml[base]; ll[ch] = ml[base + 1];
            M = fmaxf(M, mm[ch]);
        }
        float lt = 0.f;
        #pragma unroll
        for (int ch = 0; ch < 4; ++ch) {
            float wv = __expf(mm[ch] - M);
            wc[r][h][ch] = wv;
            lt += wv * ll[ch];
        }
        invl[r][h] = 1.0f / lt;
    }
    __syncthreads();
    // combine O -> Asm bf16
    {
        int r = t >> 4, c0 = t & 15;
        #pragma unroll
        for (int cc = 0; cc < 16; ++cc) {
            int c = cc * 16 + c0;
            int h = c >> 5;
            float v = wc[r][h][0] * Opart[((long)(0 * NN + r0 + r)) * HIDD + c]
                    + wc[r][h][1] * Opart[((long)(1 * NN + r0 + r)) * HIDD + c]
                    + wc[r][h][2] * Opart[((long)(2 * NN + r0 + r)) * HIDD + c]
                    + wc[r][h][3] * Opart[((long)(3 * NN + r0 + r)) * HIDD + c];
            Asm[r * PS + c] = f2bf(v * invl[r][h]);
        }
    }
    __syncthreads();
    int l = t & 63, w = t >> 6, quad = l >> 4, lj = l & 15;
    f32x4 z = {0.f, 0.f, 0.f, 0.f};
    f32x4 acc[4] = {z, z, z, z};
    for (int ks = 0; ks < 8; ++ks) {
        short8 a = *(short8*)&Asm[lj * PS + ks * 32 + quad * 8];
        #pragma unroll
        for (int nt = 0; nt < 4; ++nt) {
            int col = w * 64 + nt * 16 + lj;
            short8 bfr = *(const short8*)&WoT[col * HIDD + ks * 32 + quad * 8];
            acc[nt] = __builtin_amdgcn_mfma_f32_16x16x32_bf16(a, bfr, acc[nt], 0, 0, 0);
        }
    }
    #pragma unroll
    for (int nt = 0; nt < 4; ++nt) {
        int col = w * 64 + nt * 16 + lj;
        float bb = bo[col];
        #pragma unroll
        for (int r = 0; r < 4; ++r)
            Osm[quad * 4 + r][col] = acc[nt][r] + bb;
    }
    __syncthreads();
    #pragma unroll
    for (int rr = 0; rr < 4; ++rr) {
        int row = w * 4 + rr;
        float4 o  = *(float4*)&Osm[row][l * 4];
        float4 s4 = *(const float4*)&xres[(r0 + row) * HIDD + l * 4];
        float x0 = o.x + s4.x, x1 = o.y + s4.y, x2 = o.z + s4.z, x3 = o.w + s4.w;
        float sum = x0 + x1 + x2 + x3;
        float ss  = x0 * x0 + x1 * x1 + x2 * x2 + x3 * x3;
        #pragma unroll
        for (int off = 32; off > 0; off >>= 1) {
            sum += __shfl_xor(sum, off, 64);
            ss  += __shfl_xor(ss,  off, 64);
        }
        float mean = sum * (1.0f / HIDD);
        float var  = ss * (1.0f / HIDD) - mean * mean;
        float rstd = rsqrtf(var + 1e-5f);
        float4 ov;
        ov.x = (x0 - mean) * rstd * Lg[l * 4]     + Lb[l * 4];
        ov.y = (x1 - mean) * rstd * Lg[l * 4 + 1] + Lb[l * 4 + 1];
        ov.z = (x2 - mean) * rstd * Lg[l * 4 + 2] + Lb[l * 4 + 2];
        ov.w = (x3 - mean) * rstd * Lg[l * 4 + 3] + Lb[l * 4 + 3];
        *(float4*)&out[(r0 + row) * HIDD + l * 4] = ov;
    }
}

// ---------------- host ----------------

extern "C" void kernel_launch(void* const* d_in, const int* in_sizes, int n_in,
                              void* d_out, int out_size, void* d_ws, size_t ws_size,
                              hipStream_t stream) {
    const float* src  = (const float*)d_in[0];
    const float* tgt  = (const float*)d_in[1];
    const float* pos  = (const float*)d_in[2];
    const int*   ei   = (const int*)d_in[3];
    const float* Wq   = (const float*)d_in[4];  const float* bq  = (const float*)d_in[5];
    const float* Wk   = (const float*)d_in[6];  const float* bk  = (const float*)d_in[7];
    const float* Wv   = (const float*)d_in[8];  const float* bv  = (const float*)d_in[9];
    const float* gw1  = (const float*)d_in[10]; const float* gb1 = (const float*)d_in[11];
    const float* gw2  = (const float*)d_in[12]; const float* gb2 = (const float*)d_in[13];
    const float* tw1  = (const float*)d_in[14]; const float* tb1 = (const float*)d_in[15];
    const float* tw2  = (const float*)d_in[16]; const float* tb2 = (const float*)d_in[17];
    const float* gaw1 = (const float*)d_in[18]; const float* gab1= (const float*)d_in[19];
    const float* gaw2 = (const float*)d_in[20]; const float* gab2= (const float*)d_in[21];
    const float* Wo   = (const float*)d_in[22]; const float* bo  = (const float*)d_in[23];
    const float* lng  = (const float*)d_in[24]; const float* lnb = (const float*)d_in[25];
    int E = in_sizes[3] / 2;

    char* w = (char*)d_ws;
    unsigned* acol = (unsigned*)w; w += NN * NW * 4;        // zeroed
    unsigned* p0   = (unsigned*)w; w += NN * NW * 4;        // zeroed (contiguous)
    float* glog    = (float*)w;    w += NN * 2 * 4;         // zeroed (contiguous)
    unsigned* p1   = (unsigned*)w; w += NN * NW * 4;
    unsigned short* src_bf = (unsigned short*)w; w += NN * HIDD * 2;
    unsigned short* tgt_bf = (unsigned short*)w; w += NN * HIDD * 2;
    unsigned short* gateA  = (unsigned short*)w; w += NN * 512 * 2;
    unsigned short* WqT    = (unsigned short*)w; w += HIDD * HIDD * 2;
    unsigned short* WkT    = (unsigned short*)w; w += HIDD * HIDD * 2;
    unsigned short* WvT    = (unsigned short*)w; w += HIDD * HIDD * 2;
    unsigned short* WoT    = (unsigned short*)w; w += HIDD * HIDD * 2;
    unsigned short* gaw1T  = (unsigned short*)w; w += 1024 * 512 * 2;
    unsigned short* q_bf   = (unsigned short*)w; w += NN * HIDD * 2;
    unsigned short* k_bf   = (unsigned short*)w; w += NN * HIDD * 2;
    unsigned short* vT     = (unsigned short*)w; w += HIDD * NN * 2;   // [256][1024]
    float* t01  = (float*)w; w += 256;
    float* Opart = (float*)w; w += (long)4 * NN * HIDD * 4;  // 4 MB
    float* mlb   = (float*)w; w += (long)4 * NN * NH * 2 * 4; // 256 KB

    int nsc = (E + 255) / 256;

    // zero acol + p0 + glog (contiguous)
    hipMemsetAsync(acol, 0, 2 * NN * NW * 4 + NN * 2 * 4, stream);

    prep_kernel<<<2817 + nsc, 256, 0, stream>>>(src, tgt, Wq, Wk, Wv, Wo, gaw1,
                                                tw1, tb1, tw2, tb2, ei, E,
                                                src_bf, tgt_bf, gateA,
                                                WqT, WkT, WvT, WoT, gaw1T, t01,
                                                p0, acol);

    path_iter_kernel<<<NN / 8, 256, 0, stream>>>(p0, acol, p1);
    path_iter_kernel<<<NN / 8, 256, 0, stream>>>(p1, acol, p0);
    path_iter_kernel<<<NN / 8, 256, 0, stream>>>(p0, acol, p1);   // final path in p1

    proj_kernel<<<448, 256, 0, stream>>>(src_bf, tgt_bf, gateA, WqT, WkT, WvT, gaw1T,
                                         bq, bk, bv, gab1, gaw2,
                                         q_bf, k_bf, vT, glog);

    flash_kernel<<<dim3(4, 64), 256, 0, stream>>>(q_bf, k_bf, vT, pos, glog, gab2,
                                                  p1, t01, gw1, gb1, gw2, gb2,
                                                  Opart, mlb);

    wo_ln_kernel<<<NN / 16, 256, 0, stream>>>(Opart, mlb, WoT, bo, src, lng, lnb,
                                              (float*)d_out);
}

// Round 7
// 289.541 us; speedup vs baseline: 1.0936x; 1.0001x over previous
//
#include <hip/hip_runtime.h>
#include <math.h>

#define NN   1024
#define HIDD 256
#define NH   8
#define NW   32   // 1024 bits / 32 per word
#define MC   128  // flash m-chunk size
#define NCH  8    // flash chunks
#define GS   130  // geo2 row stride (dwords) — quad banks 0/8/16/24, 2-way free
#define PSW  136  // Pb row stride (shorts)

typedef __attribute__((ext_vector_type(8))) short short8;
typedef __attribute__((ext_vector_type(4))) float f32x4;

__device__ __forceinline__ float silu_f(float x) {
    return x / (1.0f + __expf(-x));
}
__device__ __forceinline__ unsigned short f2bf(float x) {
    unsigned b = __float_as_uint(x);
    return (unsigned short)((b + 0x7FFFu + ((b >> 16) & 1u)) >> 16);
}
__device__ __forceinline__ float bf2f(unsigned u) {
    return __uint_as_float(u << 16);
}

// ---------------- fused prep ----------------

__global__ __launch_bounds__(256)
void prep_kernel(const float* __restrict__ src, const float* __restrict__ tgt,
                 const float* __restrict__ Wq, const float* __restrict__ Wk,
                 const float* __restrict__ Wv, const float* __restrict__ Wo,
                 const float* __restrict__ gaw1,
                 const float* __restrict__ tw1, const float* __restrict__ tb1,
                 const float* __restrict__ tw2, const float* __restrict__ tb2,
                 const int* __restrict__ ei, int E,
                 unsigned short* __restrict__ src_bf, unsigned short* __restrict__ tgt_bf,
                 unsigned short* __restrict__ gateA,
                 unsigned short* __restrict__ WqT, unsigned short* __restrict__ WkT,
                 unsigned short* __restrict__ WvT, unsigned short* __restrict__ WoT,
                 unsigned short* __restrict__ gaw1T,
                 float* __restrict__ t01,
                 unsigned* __restrict__ prow, unsigned* __restrict__ acol) {
    __shared__ float tile[32][33];
    int b = blockIdx.x, t = threadIdx.x;
    if (b < 2048) {
        int idx = b * 256 + t;
        int n = idx >> 9, j = idx & 511;
        if (j < 256) {
            unsigned short u = f2bf(src[n * 256 + j]);
            src_bf[n * 256 + j] = u;
            gateA[n * 512 + j]  = u;
        } else {
            int jj = j - 256;
            unsigned short u = f2bf(tgt[n * 256 + jj]);
            tgt_bf[n * 256 + jj] = u;
            gateA[n * 512 + j]   = u;
        }
    } else if (b < 2816) {
        const float* W; unsigned short* Wt; int Kd, Nd, n0, k0;
        if (b < 2304) {
            int b2 = b - 2048;
            int which = b2 >> 6, tl = b2 & 63;
            W  = (which == 0) ? Wq : (which == 1) ? Wk : (which == 2) ? Wv : Wo;
            Wt = (which == 0) ? WqT : (which == 1) ? WkT : (which == 2) ? WvT : WoT;
            Kd = 256; Nd = 256;
            n0 = (tl & 7) * 32; k0 = (tl >> 3) * 32;
        } else {
            int b2 = b - 2304;
            W = gaw1; Wt = gaw1T; Kd = 512; Nd = 1024;
            n0 = (b2 & 31) * 32; k0 = (b2 >> 5) * 32;
        }
        int tx = t & 31, ty = t >> 5;
        #pragma unroll
        for (int p = 0; p < 4; ++p)
            tile[ty + p * 8][tx] = W[(k0 + ty + p * 8) * (long)Nd + n0 + tx];
        __syncthreads();
        #pragma unroll
        for (int p = 0; p < 4; ++p)
            Wt[(n0 + ty + p * 8) * (long)Kd + k0 + tx] = f2bf(tile[tx][ty + p * 8]);
    } else if (b == 2816) {
        if (t < 16) {
            int h = t & 7;
            float x = (t >> 3) ? 1.0f : 0.0f;
            float acc = tb2[h];
            for (int c = 0; c < 32; ++c)
                acc += silu_f(x * tw1[c] + tb1[c]) * tw2[c * 8 + h];
            t01[t] = acc;
        }
    } else {
        int e = (b - 2817) * 256 + t;
        if (e < E) {
            int r = ei[e], c = ei[E + e];
            if ((unsigned)r < NN && (unsigned)c < NN) {
                atomicOr(&prow[r * NW + (c >> 5)], 1u << (c & 31));
                atomicOr(&acol[c * NW + (r >> 5)], 1u << (r & 31));
            }
        }
    }
}

// ---------------- path propagation (8 rows / block) ----------------

__global__ __launch_bounds__(256)
void path_iter_kernel(const unsigned* __restrict__ pin,
                      const unsigned* __restrict__ acol,
                      unsigned* __restrict__ pout) {
    __shared__ unsigned pr8[8][NW];
    int t  = threadIdx.x;
    int ty = t >> 5;
    int wj = t & 31;
    int i  = blockIdx.x * 8 + ty;
    pr8[ty][wj] = pin[i * NW + wj];
    __syncthreads();
    uint4 pr[8];
    #pragma unroll
    for (int p = 0; p < 8; ++p) pr[p] = *(const uint4*)&pr8[ty][p * 4];
    unsigned inw  = pr8[ty][wj];
    unsigned outw = 0u;
    for (int b = 0; b < 32; ++b) {
        int j = (wj << 5) | b;
        const uint4* ac4 = (const uint4*)&acol[j * NW];
        unsigned x0 = 0, x1 = 0, x2 = 0, x3 = 0;
        #pragma unroll
        for (int p = 0; p < 8; ++p) {
            uint4 a = ac4[p];
            x0 |= pr[p].x & a.x;
            x1 |= pr[p].y & a.y;
            x2 |= pr[p].z & a.z;
            x3 |= pr[p].w & a.w;
        }
        outw |= (((x0 | x1) | (x2 | x3)) ? 1u : 0u) << b;
    }
    pout[i * NW + wj] = inw & outw;
}

// ---------------- shared MFMA 64x64 tile ----------------

__device__ __forceinline__ void mfma_tile64(const unsigned short* __restrict__ A,
                                            const unsigned short* __restrict__ Bt,
                                            int K, int i0, int j0, int t,
                                            f32x4 acc[2][2],
                                            unsigned short* As, unsigned short* Bs) {
    int l = t & 63, w = t >> 6;
    int wi = w >> 1, wj = w & 1;
    int quad = l >> 4, lj = l & 15;
    int sr = t >> 2, skp = (t & 3) * 8;
    f32x4 z = {0.f, 0.f, 0.f, 0.f};
    acc[0][0] = z; acc[0][1] = z; acc[1][0] = z; acc[1][1] = z;
    for (int k0 = 0; k0 < K; k0 += 32) {
        *(int4*)&As[sr * 32 + skp] = *(const int4*)&A[(i0 + sr) * (long)K + k0 + skp];
        *(int4*)&Bs[sr * 32 + skp] = *(const int4*)&Bt[(j0 + sr) * (long)K + k0 + skp];
        __syncthreads();
        short8 a0 = *(short8*)&As[(wi * 32 + lj) * 32 + quad * 8];
        short8 a1 = *(short8*)&As[(wi * 32 + 16 + lj) * 32 + quad * 8];
        short8 b0 = *(short8*)&Bs[(wj * 32 + lj) * 32 + quad * 8];
        short8 b1 = *(short8*)&Bs[(wj * 32 + 16 + lj) * 32 + quad * 8];
        acc[0][0] = __builtin_amdgcn_mfma_f32_16x16x32_bf16(a0, b0, acc[0][0], 0, 0, 0);
        acc[0][1] = __builtin_amdgcn_mfma_f32_16x16x32_bf16(a0, b1, acc[0][1], 0, 0, 0);
        acc[1][0] = __builtin_amdgcn_mfma_f32_16x16x32_bf16(a1, b0, acc[1][0], 0, 0, 0);
        acc[1][1] = __builtin_amdgcn_mfma_f32_16x16x32_bf16(a1, b1, acc[1][1], 0, 0, 0);
        __syncthreads();
    }
}

// ---------------- projections: QKV (192) + gate hidden w/ fused logits (256) --

__global__ __launch_bounds__(256)
void proj_kernel(const unsigned short* __restrict__ src_bf,
                 const unsigned short* __restrict__ tgt_bf,
                 const unsigned short* __restrict__ gateA,
                 const unsigned short* __restrict__ WqT,
                 const unsigned short* __restrict__ WkT,
                 const unsigned short* __restrict__ WvT,
                 const unsigned short* __restrict__ gaw1T,
                 const float* __restrict__ bq, const float* __restrict__ bk,
                 const float* __restrict__ bv, const float* __restrict__ gab1,
                 const float* __restrict__ gaw2,
                 unsigned short* __restrict__ q_bf, unsigned short* __restrict__ k_bf,
                 unsigned short* __restrict__ vT, float* __restrict__ glog) {
    __shared__ unsigned short As[64 * 32];
    __shared__ unsigned short Bs[64 * 32];
    int b = blockIdx.x, t = threadIdx.x;
    int l = t & 63, w = t >> 6, wi = w >> 1, wjq = w & 1, quad = l >> 4, lj = l & 15;
    f32x4 acc[2][2];
    if (b < 192) {
        int z = b >> 6, rem = b & 63;
        int j0 = (rem & 3) * 64, i0 = (rem >> 2) * 64;
        const unsigned short* A  = (z == 0) ? src_bf : tgt_bf;
        const unsigned short* Bt = (z == 0) ? WqT : (z == 1) ? WkT : WvT;
        const float* bias        = (z == 0) ? bq : (z == 1) ? bk : bv;
        mfma_tile64(A, Bt, HIDD, i0, j0, t, acc, As, Bs);
        #pragma unroll
        for (int rg = 0; rg < 2; ++rg)
            #pragma unroll
            for (int cg = 0; cg < 2; ++cg) {
                int col  = j0 + wjq * 32 + cg * 16 + lj;
                int row0 = i0 + wi * 32 + rg * 16 + quad * 4;
                float bb = bias[col];
                if (z < 2) {
                    unsigned short* obf = (z == 0) ? q_bf : k_bf;
                    #pragma unroll
                    for (int r = 0; r < 4; ++r)
                        obf[(row0 + r) * HIDD + col] = f2bf(acc[rg][cg][r] + bb);
                } else {
                    unsigned short vv[4];
                    #pragma unroll
                    for (int r = 0; r < 4; ++r) vv[r] = f2bf(acc[rg][cg][r] + bb);
                    *(int2*)&vT[col * NN + row0] = *(int2*)vv;
                }
            }
    } else {
        int b2 = b - 192;
        int j0 = (b2 & 15) * 64, i0 = (b2 >> 4) * 64;
        mfma_tile64(gateA, gaw1T, 512, i0, j0, t, acc, As, Bs);
        float p[8][2];
        #pragma unroll
        for (int s = 0; s < 8; ++s) { p[s][0] = 0.f; p[s][1] = 0.f; }
        #pragma unroll
        for (int cg = 0; cg < 2; ++cg) {
            int col = j0 + wjq * 32 + cg * 16 + lj;
            float w20 = gaw2[col * 2], w21 = gaw2[col * 2 + 1];
            float bb = gab1[col];
            #pragma unroll
            for (int rg = 0; rg < 2; ++rg)
                #pragma unroll
                for (int r = 0; r < 4; ++r) {
                    float hv = silu_f(acc[rg][cg][r] + bb);
                    p[rg * 4 + r][0] += hv * w20;
                    p[rg * 4 + r][1] += hv * w21;
                }
        }
        #pragma unroll
        for (int off = 1; off < 16; off <<= 1)
            #pragma unroll
            for (int s = 0; s < 8; ++s) {
                p[s][0] += __shfl_xor(p[s][0], off, 64);
                p[s][1] += __shfl_xor(p[s][1], off, 64);
            }
        if (lj == 0) {
            #pragma unroll
            for (int rg = 0; rg < 2; ++rg)
                #pragma unroll
                for (int r = 0; r < 4; ++r) {
                    int row = i0 + wi * 32 + rg * 16 + quad * 4 + r;
                    atomicAdd(&glog[row * 2],     p[rg * 4 + r][0]);
                    atomicAdd(&glog[row * 2 + 1], p[rg * 4 + r][1]);
                }
        }
    }
}

// ---------------- flash attention v2 ----------------
// grid (8 m-chunks of 128, 64 row-tiles of 16). 4 waves; wave w handles
// heads w and w+4 fully independently (wave-internal softmax + private P
// buffer). Only 2 barriers per block (after preamble, after geo phase).

__global__ __launch_bounds__(256)
void flash_kernel(const unsigned short* __restrict__ qbf,
                  const unsigned short* __restrict__ kbf,
                  const unsigned short* __restrict__ vT,
                  const float* __restrict__ pos, const float* __restrict__ glog,
                  const float* __restrict__ gab2,
                  const unsigned* __restrict__ pbits, const float* __restrict__ t01,
                  const float* __restrict__ gw1, const float* __restrict__ gb1,
                  const float* __restrict__ gw2, const float* __restrict__ gb2,
                  float* __restrict__ Opart, float* __restrict__ ml) {
    __shared__ unsigned geo2[4 * 16 * GS];      // 33.3 KB [h/2][i][j]
    __shared__ unsigned short Pb[4 * 16 * PSW]; // 17.4 KB, wave-private quarters
    __shared__ float posA[48], posB[384];
    __shared__ unsigned prowL[64];              // 16 rows x 4 words
    __shared__ float g01[32];
    __shared__ float w1s[32], b1s[32], w2s[256], b2s[8], t01s[16];
    int t  = threadIdx.x;
    int bx = blockIdx.x;               // m-chunk
    int n0 = blockIdx.y * 16;
    int mbase = bx * MC;
    w2s[t] = gw2[t];
    posB[t > 255 ? 0 : t] = pos[mbase * 3 + (t > 255 ? 0 : t)];
    if (t < MC) posB[256 + t] = pos[mbase * 3 + 256 + t];
    if (t < 48)  posA[t] = pos[n0 * 3 + t];
    if (t < 64)  prowL[t] = pbits[(n0 + (t >> 2)) * NW + bx * 4 + (t & 3)];
    if (t < 16) {
        float L0 = glog[(n0 + t) * 2]     + gab2[0];
        float L1 = glog[(n0 + t) * 2 + 1] + gab2[1];
        float mx = fmaxf(L0, L1);
        float e0 = __expf(L0 - mx), e1 = __expf(L1 - mx);
        float inv = 1.0f / (e0 + e1);
        g01[2 * t]     = e0 * inv;
        g01[2 * t + 1] = e1 * inv;
    }
    if (t < 32) { w1s[t] = gw1[t]; b1s[t] = gb1[t]; }
    if (t < 16) t01s[t] = t01[t];
    if (t < 8)  b2s[t] = gb2[t];
    __syncthreads();

    // phase 1: geo MLP, 2048 pairs, 8 per thread
    for (int pp = 0; pp < 8; ++pp) {
        int p = pp * 256 + t;
        int i = p >> 7, j = p & (MC - 1);
        float dx = posA[i * 3]     - posB[j * 3];
        float dy = posA[i * 3 + 1] - posB[j * 3 + 1];
        float dz = posA[i * 3 + 2] - posB[j * 3 + 2];
        float dist = sqrtf(fmaxf(dx * dx + dy * dy + dz * dz, 1e-12f));
        float go[8];
        #pragma unroll
        for (int h = 0; h < 8; ++h) go[h] = b2s[h];
        #pragma unroll 4
        for (int c = 0; c < 32; ++c) {
            float hh = silu_f(dist * w1s[c] + b1s[c]);
            #pragma unroll
            for (int h = 0; h < 8; ++h) go[h] += hh * w2s[c * 8 + h];
        }
        #pragma unroll
        for (int h2 = 0; h2 < 4; ++h2)
            geo2[h2 * 16 * GS + i * GS + j] = (unsigned)f2bf(go[2 * h2]) |
                                              ((unsigned)f2bf(go[2 * h2 + 1]) << 16);
    }
    __syncthreads();

    int l = t & 63, w = t >> 6, quad = l >> 4, lj = l & 15;
    unsigned short* Pw = &Pb[w * 16 * PSW];
    const float scale = 0.17677669529663687f;  // 1/sqrt(32)
    f32x4 z = {0.f, 0.f, 0.f, 0.f};

    #pragma unroll
    for (int hi = 0; hi < 2; ++hi) {
        int h = w + hi * 4;
        // QK: 8 col-tiles of 16
        short8 a = *(const short8*)&qbf[(n0 + lj) * HIDD + h * 32 + quad * 8];
        f32x4 acc[8];
        #pragma unroll
        for (int tl = 0; tl < 8; ++tl) {
            short8 bfr = *(const short8*)&kbf[(mbase + tl * 16 + lj) * HIDD +
                                              h * 32 + quad * 8];
            acc[tl] = __builtin_amdgcn_mfma_f32_16x16x32_bf16(a, bfr, z, 0, 0, 0);
        }
        // bias add: row i=quad*4+r, col j=tl*16+lj
        #pragma unroll
        for (int tl = 0; tl < 8; ++tl) {
            int j = tl * 16 + lj;
            #pragma unroll
            for (int r = 0; r < 4; ++r) {
                int i = quad * 4 + r;
                unsigned gv = geo2[(h >> 1) * 16 * GS + i * GS + j];
                float geo_v = bf2f((h & 1) ? (gv >> 16) : (gv & 0xffffu));
                unsigned bit = (prowL[i * 4 + (j >> 5)] >> (j & 31)) & 1u;
                acc[tl][r] = acc[tl][r] * scale + g01[2 * i] * geo_v +
                             g01[2 * i + 1] * t01s[bit * 8 + h];
            }
        }
        // wave-internal row max (quads own disjoint rows; reduce over 16 lj)
        float mr[4];
        #pragma unroll
        for (int r = 0; r < 4; ++r) {
            float m01 = fmaxf(fmaxf(acc[0][r], acc[1][r]), fmaxf(acc[2][r], acc[3][r]));
            float m23 = fmaxf(fmaxf(acc[4][r], acc[5][r]), fmaxf(acc[6][r], acc[7][r]));
            mr[r] = fmaxf(m01, m23);
        }
        #pragma unroll
        for (int off = 1; off < 16; off <<= 1)
            #pragma unroll
            for (int r = 0; r < 4; ++r) mr[r] = fmaxf(mr[r], __shfl_xor(mr[r], off, 64));
        // exp, P -> wave-private LDS (A-layout), row sums
        float sm[4] = {0.f, 0.f, 0.f, 0.f};
        #pragma unroll
        for (int tl = 0; tl < 8; ++tl) {
            int j = tl * 16 + lj;
            #pragma unroll
            for (int r = 0; r < 4; ++r) {
                float e = __expf(acc[tl][r] - mr[r]);
                Pw[(quad * 4 + r) * PSW + j] = f2bf(e);
                sm[r] += e;
            }
        }
        #pragma unroll
        for (int off = 1; off < 16; off <<= 1)
            #pragma unroll
            for (int r = 0; r < 4; ++r) sm[r] += __shfl_xor(sm[r], off, 64);
        if (lj == 0) {
            #pragma unroll
            for (int r = 0; r < 4; ++r) {
                int i = quad * 4 + r;
                int base = ((bx * NN + n0 + i) * NH + h) * 2;
                ml[base] = mr[r]; ml[base + 1] = sm[r];
            }
        }
        // PV: K=128, 2 d-tiles; same-wave DS ordering makes this safe w/o barrier
        f32x4 o[2] = {z, z};
        #pragma unroll
        for (int ks = 0; ks < 4; ++ks) {
            short8 aP = *(short8*)&Pw[lj * PSW + ks * 32 + quad * 8];
            #pragma unroll
            for (int dt = 0; dt < 2; ++dt) {
                short8 bV = *(const short8*)&vT[(h * 32 + dt * 16 + lj) * NN +
                                                mbase + ks * 32 + quad * 8];
                o[dt] = __builtin_amdgcn_mfma_f32_16x16x32_bf16(aP, bV, o[dt], 0, 0, 0);
            }
        }
        #pragma unroll
        for (int dt = 0; dt < 2; ++dt)
            #pragma unroll
            for (int r = 0; r < 4; ++r)
                Opart[((long)(bx * NN + n0 + quad * 4 + r)) * HIDD +
                      h * 32 + dt * 16 + lj] = o[dt][r];
    }
}

// ---------------- combine + Wo projection + residual + LayerNorm ----------------

#define PS 264

__global__ __launch_bounds__(256)
void wo_ln_kernel(const float* __restrict__ Opart, const float* __restrict__ ml,
                  const unsigned short* __restrict__ WoT,
                  const float* __restrict__ bo, const float* __restrict__ xres,
                  const float* __restrict__ lng, const float* __restrict__ lnb,
                  float* __restrict__ out) {
    __shared__ unsigned short Asm[16 * PS];
    __shared__ float Osm[16][260];
    __shared__ float Lg[256], Lb[256];
    __shared__ float wc[16][NH][NCH];
    __shared__ float invl[16][NH];
    int t = threadIdx.x;
    int r0 = blockIdx.x * 16;
    Lg[t] = lng[t]; Lb[t] = lnb[t];
    if (t < 128) {
        int r = t >> 3, h = t & 7;
        float mm[NCH], ll[NCH];
        float M = -1e30f;
        #pragma unroll
        for (int ch = 0; ch < NCH; ++ch) {
            int base = ((ch * NN + r0 + r) * NH + h) * 2;
            mm[ch] = ml[base]; ll[ch] = ml[base + 1];
            M = fmaxf(M, mm[ch]);
        }
        float lt = 0.f;
        #pragma unroll
        for (int ch = 0; ch < NCH; ++ch) {
            float wv = __expf(mm[ch] - M);
            wc[r][h][ch] = wv;
            lt += wv * ll[ch];
        }
        invl[r][h] = 1.0f / lt;
    }
    __syncthreads();
    {
        int r = t >> 4, c0 = t & 15;
        #pragma unroll
        for (int cc = 0; cc < 16; ++cc) {
            int c = cc * 16 + c0;
            int h = c >> 5;
            float v = 0.f;
            #pragma unroll
            for (int ch = 0; ch < NCH; ++ch)
                v += wc[r][h][ch] * Opart[((long)(ch * NN + r0 + r)) * HIDD + c];
            Asm[r * PS + c] = f2bf(v * invl[r][h]);
        }
    }
    __syncthreads();
    int l = t & 63, w = t >> 6, quad = l >> 4, lj = l & 15;
    f32x4 z = {0.f, 0.f, 0.f, 0.f};
    f32x4 acc[4] = {z, z, z, z};
    for (int ks = 0; ks < 8; ++ks) {
        short8 a = *(short8*)&Asm[lj * PS + ks * 32 + quad * 8];
        #pragma unroll
        for (int nt = 0; nt < 4; ++nt) {
            int col = w * 64 + nt * 16 + lj;
            short8 bfr = *(const short8*)&WoT[col * HIDD + ks * 32 + quad * 8];
            acc[nt] = __builtin_amdgcn_mfma_f32_16x16x32_bf16(a, bfr, acc[nt], 0, 0, 0);
        }
    }
    #pragma unroll
    for (int nt = 0; nt < 4; ++nt) {
        int col = w * 64 + nt * 16 + lj;
        float bb = bo[col];
        #pragma unroll
        for (int r = 0; r < 4; ++r)
            Osm[quad * 4 + r][col] = acc[nt][r] + bb;
    }
    __syncthreads();
    #pragma unroll
    for (int rr = 0; rr < 4; ++rr) {
        int row = w * 4 + rr;
        float4 o  = *(float4*)&Osm[row][l * 4];
        float4 s4 = *(const float4*)&xres[(r0 + row) * HIDD + l * 4];
        float x0 = o.x + s4.x, x1 = o.y + s4.y, x2 = o.z + s4.z, x3 = o.w + s4.w;
        float sum = x0 + x1 + x2 + x3;
        float ss  = x0 * x0 + x1 * x1 + x2 * x2 + x3 * x3;
        #pragma unroll
        for (int off = 32; off > 0; off >>= 1) {
            sum += __shfl_xor(sum, off, 64);
            ss  += __shfl_xor(ss,  off, 64);
        }
        float mean = sum * (1.0f / HIDD);
        float var  = ss * (1.0f / HIDD) - mean * mean;
        float rstd = rsqrtf(var + 1e-5f);
        float4 ov;
        ov.x = (x0 - mean) * rstd * Lg[l * 4]     + Lb[l * 4];
        ov.y = (x1 - mean) * rstd * Lg[l * 4 + 1] + Lb[l * 4 + 1];
        ov.z = (x2 - mean) * rstd * Lg[l * 4 + 2] + Lb[l * 4 + 2];
        ov.w = (x3 - mean) * rstd * Lg[l * 4 + 3] + Lb[l * 4 + 3];
        *(float4*)&out[(r0 + row) * HIDD + l * 4] = ov;
    }
}

// ---------------- host ----------------

extern "C" void kernel_launch(void* const* d_in, const int* in_sizes, int n_in,
                              void* d_out, int out_size, void* d_ws, size_t ws_size,
                              hipStream_t stream) {
    const float* src  = (const float*)d_in[0];
    const float* tgt  = (const float*)d_in[1];
    const float* pos  = (const float*)d_in[2];
    const int*   ei   = (const int*)d_in[3];
    const float* Wq   = (const float*)d_in[4];  const float* bq  = (const float*)d_in[5];
    const float* Wk   = (const float*)d_in[6];  const float* bk  = (const float*)d_in[7];
    const float* Wv   = (const float*)d_in[8];  const float* bv  = (const float*)d_in[9];
    const float* gw1  = (const float*)d_in[10]; const float* gb1 = (const float*)d_in[11];
    const float* gw2  = (const float*)d_in[12]; const float* gb2 = (const float*)d_in[13];
    const float* tw1  = (const float*)d_in[14]; const float* tb1 = (const float*)d_in[15];
    const float* tw2  = (const float*)d_in[16]; const float* tb2 = (const float*)d_in[17];
    const float* gaw1 = (const float*)d_in[18]; const float* gab1= (const float*)d_in[19];
    const float* gaw2 = (const float*)d_in[20]; const float* gab2= (const float*)d_in[21];
    const float* Wo   = (const float*)d_in[22]; const float* bo  = (const float*)d_in[23];
    const float* lng  = (const float*)d_in[24]; const float* lnb = (const float*)d_in[25];
    int E = in_sizes[3] / 2;

    char* w = (char*)d_ws;
    unsigned* acol = (unsigned*)w; w += NN * NW * 4;        // zeroed
    unsigned* p0   = (unsigned*)w; w += NN * NW * 4;        // zeroed (contiguous)
    float* glog    = (float*)w;    w += NN * 2 * 4;         // zeroed (contiguous)
    unsigned* p1   = (unsigned*)w; w += NN * NW * 4;
    unsigned short* src_bf = (unsigned short*)w; w += NN * HIDD * 2;
    unsigned short* tgt_bf = (unsigned short*)w; w += NN * HIDD * 2;
    unsigned short* gateA  = (unsigned short*)w; w += NN * 512 * 2;
    unsigned short* WqT    = (unsigned short*)w; w += HIDD * HIDD * 2;
    unsigned short* WkT    = (unsigned short*)w; w += HIDD * HIDD * 2;
    unsigned short* WvT    = (unsigned short*)w; w += HIDD * HIDD * 2;
    unsigned short* WoT    = (unsigned short*)w; w += HIDD * HIDD * 2;
    unsigned short* gaw1T  = (unsigned short*)w; w += 1024 * 512 * 2;
    unsigned short* q_bf   = (unsigned short*)w; w += NN * HIDD * 2;
    unsigned short* k_bf   = (unsigned short*)w; w += NN * HIDD * 2;
    unsigned short* vT     = (unsigned short*)w; w += HIDD * NN * 2;   // [256][1024]
    float* t01  = (float*)w; w += 256;
    float* Opart = (float*)w; w += (long)NCH * NN * HIDD * 4;   // 8 MB
    float* mlb   = (float*)w; w += (long)NCH * NN * NH * 2 * 4; // 512 KB

    int nsc = (E + 255) / 256;

    // zero acol + p0 + glog (contiguous)
    hipMemsetAsync(acol, 0, 2 * NN * NW * 4 + NN * 2 * 4, stream);

    prep_kernel<<<2817 + nsc, 256, 0, stream>>>(src, tgt, Wq, Wk, Wv, Wo, gaw1,
                                                tw1, tb1, tw2, tb2, ei, E,
                                                src_bf, tgt_bf, gateA,
                                                WqT, WkT, WvT, WoT, gaw1T, t01,
                                                p0, acol);

    path_iter_kernel<<<NN / 8, 256, 0, stream>>>(p0, acol, p1);
    path_iter_kernel<<<NN / 8, 256, 0, stream>>>(p1, acol, p0);
    path_iter_kernel<<<NN / 8, 256, 0, stream>>>(p0, acol, p1);   // final path in p1

    proj_kernel<<<448, 256, 0, stream>>>(src_bf, tgt_bf, gateA, WqT, WkT, WvT, gaw1T,
                                         bq, bk, bv, gab1, gaw2,
                                         q_bf, k_bf, vT, glog);

    flash_kernel<<<dim3(NCH, 64), 256, 0, stream>>>(q_bf, k_bf, vT, pos, glog, gab2,
                                                    p1, t01, gw1, gb1, gw2, gb2,
                                                    Opart, mlb);

    wo_ln_kernel<<<NN / 16, 256, 0, stream>>>(Opart, mlb, WoT, bo, src, lng, lnb,
                                              (float*)d_out);
}